// Round 3
// baseline (1917.279 us; speedup 1.0000x reference)
//
#include <hip/hip_runtime.h>
#include <math.h>

#define SD 10
#define BB 8                  // bucket bits
#define BSZ 256               // nodes per bucket
#define MAXNB 1024            // max buckets supported (N <= 262144)
#define EB 256                // edge-chunk blocks for passes A/C
#define CTHR 512              // threads for passes A/C

__device__ __forceinline__ float tanh_fast(float x) {
    float e = __expf(2.0f * x);
    float r = __builtin_amdgcn_rcpf(1.0f + e);
    return 1.0f - 2.0f * r;
}

__device__ __forceinline__ float softplus_f(float x) {
    return fmaxf(x, 0.0f) + log1pf(expf(-fabsf(x)));
}

__device__ __forceinline__ unsigned short bf16_of(float x) {
    unsigned u = __float_as_uint(x);
    u = (u + 0x7FFFu + ((u >> 16) & 1u)) >> 16;   // RNE
    return (unsigned short)u;
}
__device__ __forceinline__ float f_of_bf16(unsigned short h) {
    return __uint_as_float(((unsigned)h) << 16);
}

// ===================== build: deterministic multi-split =====================

// Pass A: per-block bucket histogram -> gcnt[k*EB + b]  (bucket-major)
__global__ __launch_bounds__(CTHR) void bucket_count_kernel(
    const int* __restrict__ nto, unsigned* __restrict__ gcnt, int E, int NB)
{
    __shared__ unsigned h[MAXNB];
    int b = blockIdx.x;
    for (int i = threadIdx.x; i < NB; i += CTHR) h[i] = 0;
    __syncthreads();
    long long ebeg = (long long)E * b / EB;
    long long eend = (long long)E * (b + 1) / EB;
    for (long long e = ebeg + threadIdx.x; e < eend; e += CTHR)
        atomicAdd(&h[((unsigned)nto[e]) >> BB], 1u);
    __syncthreads();
    for (int k = threadIdx.x; k < NB; k += CTHR) gcnt[(size_t)k * EB + b] = h[k];
}

// Exclusive scan, level 1: 1024 items per 256-thread block.
__global__ __launch_bounds__(256) void scan1_kernel(
    const unsigned* __restrict__ cnt, unsigned* __restrict__ off,
    unsigned* __restrict__ bsum, int M)
{
    __shared__ unsigned lds[256];
    int t = threadIdx.x, b = blockIdx.x;
    int base = b * 1024 + t * 4;
    unsigned v[4], s = 0;
#pragma unroll
    for (int k = 0; k < 4; k++) {
        v[k] = (base + k < M) ? cnt[base + k] : 0u;
        s += v[k];
    }
    lds[t] = s;
    __syncthreads();
    for (int d = 1; d < 256; d <<= 1) {
        unsigned x = (t >= d) ? lds[t - d] : 0u;
        __syncthreads();
        lds[t] += x;
        __syncthreads();
    }
    unsigned excl = (t > 0) ? lds[t - 1] : 0u;
    if (t == 255) bsum[b] = lds[255];
    unsigned run = excl;
#pragma unroll
    for (int k = 0; k < 4; k++) {
        if (base + k < M) off[base + k] = run;
        run += v[k];
    }
}

__global__ __launch_bounds__(256) void scan2_kernel(unsigned* __restrict__ bsum, int nb)
{
    __shared__ unsigned lds[256];
    int t = threadIdx.x;
    unsigned v = (t < nb) ? bsum[t] : 0u;
    lds[t] = v;
    __syncthreads();
    for (int d = 1; d < 256; d <<= 1) {
        unsigned x = (t >= d) ? lds[t - d] : 0u;
        __syncthreads();
        lds[t] += x;
        __syncthreads();
    }
    unsigned excl = (t > 0) ? lds[t - 1] : 0u;
    if (t < nb) bsum[t] = excl;
}

__global__ __launch_bounds__(256) void scan_add_kernel(
    unsigned* __restrict__ off, const unsigned* __restrict__ bsum, int M)
{
    int i = blockIdx.x * blockDim.x + threadIdx.x;
    if (i < M) off[i] += bsum[i >> 10];
}

// bstart[k] = first payload index of bucket k; bstart[NB] = E
__global__ __launch_bounds__(256) void bstart_kernel(
    const unsigned* __restrict__ gbase, unsigned* __restrict__ bstart, int NB, int E)
{
    int k = blockIdx.x * blockDim.x + threadIdx.x;
    if (k > NB) return;
    bstart[k] = (k < NB) ? gbase[(size_t)k * EB] : (unsigned)E;
}

// Pass C: emit bucket-sorted payload {packed nfrom|local_nt, bf16 geo}
__global__ __launch_bounds__(CTHR) void bucket_scatter_kernel(
    const float* __restrict__ coords,
    const float* __restrict__ elen,
    const float* __restrict__ evec,
    const int* __restrict__ nfrom,
    const int* __restrict__ nto,
    const unsigned* __restrict__ gbase,
    int* __restrict__ pk,
    ushort4* __restrict__ geo8,
    int E, int NB)
{
    __shared__ unsigned cur[MAXNB];
    int b = blockIdx.x;
    for (int k = threadIdx.x; k < NB; k += CTHR) cur[k] = gbase[(size_t)k * EB + b];
    __syncthreads();
    long long ebeg = (long long)E * b / EB;
    long long eend = (long long)E * (b + 1) / EB;
    for (long long e = ebeg + threadIdx.x; e < eend; e += CTHR) {
        int nf = nfrom[e];
        int nt = nto[e];
        unsigned k = ((unsigned)nt) >> BB;
        unsigned pos = atomicAdd(&cur[k], 1u);

        float cf0 = coords[nf * 3 + 0], cf1 = coords[nf * 3 + 1], cf2 = coords[nf * 3 + 2];
        float ct0 = coords[nt * 3 + 0], ct1 = coords[nt * 3 + 1], ct2 = coords[nt * 3 + 2];
        float ev0 = evec[e * 3 + 0], ev1 = evec[e * 3 + 1], ev2 = evec[e * 3 + 2];

        float g0 = elen[e];
        float g1 = fabsf(cf0) + fabsf(cf1) + fabsf(cf2);
        float g2 = cf0 * ct0 + cf1 * ct1 + cf2 * ct2;
        float g3 = cf0 * ev0 + cf1 * ev1 + cf2 * ev2;

        ushort4 g;
        g.x = bf16_of(g0); g.y = bf16_of(g1); g.z = bf16_of(g2); g.w = bf16_of(g3);
        pk[pos] = nf | ((nt & (BSZ - 1)) << 18);
        geo8[pos] = g;
    }
}

// ===================== rounds =====================

// Wst[n][j] = bm[j] + sum_k state[n][k] * Wm[k][j]   (hoists 10x10 matmul out of edge loop)
__global__ __launch_bounds__(256) void wstate_kernel(
    const float* __restrict__ state, const float* __restrict__ Wm,
    const float* __restrict__ bm, float* __restrict__ wst, int N)
{
    int n = blockIdx.x * blockDim.x + threadIdx.x;
    if (n >= N) return;
    const float2* sp = (const float2*)(state + (size_t)n * SD);
    float s[SD];
#pragma unroll
    for (int h = 0; h < 5; h++) { float2 v = sp[h]; s[2*h] = v.x; s[2*h+1] = v.y; }
    float t[SD];
#pragma unroll
    for (int j = 0; j < SD; j++) t[j] = bm[j];
#pragma unroll
    for (int k = 0; k < SD; k++) {
#pragma unroll
        for (int j = 0; j < SD; j++) t[j] += s[k] * Wm[k * SD + j];
    }
    float2* dp = (float2*)(wst + (size_t)n * SD);
#pragma unroll
    for (int h = 0; h < 5; h++) { float2 v; v.x = t[2*h]; v.y = t[2*h+1]; dp[h] = v; }
}

// one workgroup per bucket; LDS accumulation; no global atomics
template <bool FIRST>
__global__ __launch_bounds__(256) void round_bucket_kernel(
    const unsigned* __restrict__ bstart,
    const int* __restrict__ pk,
    const ushort4* __restrict__ geo8,
    const float* __restrict__ Wm,    // rows 10..13 = geo weights
    const float* __restrict__ bm,
    const float* __restrict__ wst,   // (N,10) incl bias (rounds 2,3)
    const float* __restrict__ state_prev,
    float* __restrict__ state_next,
    int N)
{
    __shared__ float acc[BSZ * SD];
    int k = blockIdx.x;
    for (int i = threadIdx.x; i < BSZ * SD; i += 256) acc[i] = 0.0f;

    // hoist geo weights (+bias for round 1) into registers/sgprs
    float wg0[SD], wg1[SD], wg2[SD], wg3[SD], bb[SD];
#pragma unroll
    for (int j = 0; j < SD; j++) {
        wg0[j] = Wm[10 * SD + j];
        wg1[j] = Wm[11 * SD + j];
        wg2[j] = Wm[12 * SD + j];
        wg3[j] = Wm[13 * SD + j];
        bb[j]  = FIRST ? bm[j] : 0.0f;
    }
    __syncthreads();

    unsigned beg = bstart[k], end = bstart[k + 1];
    for (unsigned i = beg + threadIdx.x; i < end; i += 256) {
        int p = pk[i];
        ushort4 g = geo8[i];
        float g0 = f_of_bf16(g.x), g1 = f_of_bf16(g.y);
        float g2 = f_of_bf16(g.z), g3 = f_of_bf16(g.w);
        int nf  = p & 0x3FFFF;
        int lnt = (p >> 18) & (BSZ - 1);

        float t[SD];
        if (FIRST) {
#pragma unroll
            for (int j = 0; j < SD; j++) t[j] = bb[j];
        } else {
            const float2* wp = (const float2*)(wst + (size_t)nf * SD);
#pragma unroll
            for (int h = 0; h < 5; h++) { float2 v = wp[h]; t[2*h] = v.x; t[2*h+1] = v.y; }
        }
#pragma unroll
        for (int j = 0; j < SD; j++) {
            t[j] += g0 * wg0[j] + g1 * wg1[j] + g2 * wg2[j] + g3 * wg3[j];
            atomicAdd(&acc[lnt * SD + j], tanh_fast(t[j]));
        }
    }
    __syncthreads();

    int base = k * BSZ * SD;
    int lim = N * SD - base;
    for (int i = threadIdx.x; i < BSZ * SD; i += 256) {
        if (i < lim) {
            float v = acc[i];
            if (!FIRST) v += state_prev[base + i];
            state_next[base + i] = v;
        }
    }
}

// ===================== graph phase =====================

__global__ __launch_bounds__(256) void goff_kernel(
    const int* __restrict__ gidx, unsigned* __restrict__ goff, int N, int G)
{
    int n = blockIdx.x * blockDim.x + threadIdx.x;
    if (n >= N) return;
    int g = gidx[n];
    if (n == 0) {
        for (int q = 0; q <= g; q++) goff[q] = 0;
    } else {
        int gp = gidx[n - 1];
        for (int q = gp + 1; q <= g; q++) goff[q] = (unsigned)n;
    }
    if (n == N - 1) {
        for (int q = g + 1; q <= G; q++) goff[q] = (unsigned)N;
    }
}

__global__ __launch_bounds__(256) void gsum_kernel(
    const float* __restrict__ state, const unsigned* __restrict__ goff,
    float* __restrict__ gstate, int G)
{
    int tid = blockIdx.x * blockDim.x + threadIdx.x;
    if (tid >= G * SD) return;
    int g = tid / SD;
    int j = tid % SD;
    unsigned beg = goff[g], end = goff[g + 1];
    float a = 0.0f;
    for (unsigned n = beg; n < end; n++) a += state[(size_t)n * SD + j];
    gstate[(size_t)g * SD + j] = a;
}

__global__ __launch_bounds__(256) void out_kernel(
    const float* __restrict__ gstate, const float* __restrict__ Wo,
    const float* __restrict__ bo, float* __restrict__ out, int G)
{
    int g = blockIdx.x * blockDim.x + threadIdx.x;
    if (g >= G) return;
    float s[SD];
#pragma unroll
    for (int k = 0; k < SD; k++) s[k] = gstate[(size_t)g * SD + k];
    float ev[4];
#pragma unroll
    for (int c = 0; c < 4; c++) {
        float a = bo[c];
#pragma unroll
        for (int k = 0; k < SD; k++) a += s[k] * Wo[k * 4 + c];
        ev[c] = a;
    }
    out[g * 4 + 0] = ev[0];
    out[g * 4 + 1] = softplus_f(ev[1]);
    out[g * 4 + 2] = softplus_f(ev[2]) + 1.0f;
    out[g * 4 + 3] = softplus_f(ev[3]);
}

// ===================== fallback (atomic path) =====================

template <bool FIRST>
__global__ __launch_bounds__(256) void edge_kernel_fb(
    const float* __restrict__ coords, const float* __restrict__ elen,
    const float* __restrict__ evec, const float* __restrict__ Wm,
    const float* __restrict__ bm, const int* __restrict__ nfrom,
    const int* __restrict__ nto, const float* __restrict__ state_prev,
    float* __restrict__ state_next, int E)
{
    int e = blockIdx.x * blockDim.x + threadIdx.x;
    if (e >= E) return;
    int nf = nfrom[e];
    int nt = nto[e];
    float cf0 = coords[nf*3+0], cf1 = coords[nf*3+1], cf2 = coords[nf*3+2];
    float ct0 = coords[nt*3+0], ct1 = coords[nt*3+1], ct2 = coords[nt*3+2];
    float ev0 = evec[e*3+0], ev1 = evec[e*3+1], ev2 = evec[e*3+2];
    float g0 = elen[e];
    float g1 = fabsf(cf0) + fabsf(cf1) + fabsf(cf2);
    float g2 = cf0*ct0 + cf1*ct1 + cf2*ct2;
    float g3 = cf0*ev0 + cf1*ev1 + cf2*ev2;
    float acc[SD];
#pragma unroll
    for (int j = 0; j < SD; j++) {
        acc[j] = bm[j] + g0*Wm[10*SD+j] + g1*Wm[11*SD+j] + g2*Wm[12*SD+j] + g3*Wm[13*SD+j];
    }
    if (!FIRST) {
        const float2* sp = (const float2*)(state_prev + (size_t)nf * SD);
        float s[SD];
#pragma unroll
        for (int h = 0; h < 5; h++) { float2 v = sp[h]; s[2*h] = v.x; s[2*h+1] = v.y; }
#pragma unroll
        for (int k = 0; k < SD; k++) {
#pragma unroll
            for (int j = 0; j < SD; j++) acc[j] += s[k] * Wm[k*SD+j];
        }
    }
    float* dst = state_next + (size_t)nt * SD;
#pragma unroll
    for (int j = 0; j < SD; j++) atomicAdd(dst + j, tanh_fast(acc[j]));
}

__global__ __launch_bounds__(256) void graph_reduce_fb(
    const float* __restrict__ state, const int* __restrict__ gidx,
    float* __restrict__ gstate, int N)
{
    int n = blockIdx.x * blockDim.x + threadIdx.x;
    if (n >= N) return;
    int g = gidx[n];
    const float2* sp = (const float2*)(state + (size_t)n * SD);
    float* dst = gstate + (size_t)g * SD;
#pragma unroll
    for (int h = 0; h < 5; h++) {
        float2 v = sp[h];
        atomicAdd(dst + 2*h, v.x);
        atomicAdd(dst + 2*h + 1, v.y);
    }
}

// ===================== launch =====================

extern "C" void kernel_launch(void* const* d_in, const int* in_sizes, int n_in,
                              void* d_out, int out_size, void* d_ws, size_t ws_size,
                              hipStream_t stream) {
    const float* coords = (const float*)d_in[0];
    const float* elen   = (const float*)d_in[1];
    const float* evec   = (const float*)d_in[2];
    const float* Wm     = (const float*)d_in[3];
    const float* bm     = (const float*)d_in[4];
    const float* Wo     = (const float*)d_in[5];
    const float* bo     = (const float*)d_in[6];
    const int* nfrom    = (const int*)d_in[7];
    const int* nto      = (const int*)d_in[8];
    const int* gidx     = (const int*)d_in[9];

    const int E = in_sizes[1];
    const int N = in_sizes[9];
    const int G = out_size / 4;

    const int NB = (N + BSZ - 1) / BSZ;         // buckets
    const int M  = NB * EB;                     // scan length
    const int nb1 = (M + 1023) / 1024;          // scan level-1 blocks

    const int BLK = 256;
    const int ng = (N + BLK - 1) / BLK;
    const int gg = (G + BLK - 1) / BLK;

    auto align256 = [](size_t x) { return (x + 255) & ~(size_t)255; };
    const size_t state_bytes = align256((size_t)N * SD * sizeof(float));
    const size_t wst_bytes   = state_bytes;
    const size_t pk_bytes    = align256((size_t)E * sizeof(int));
    const size_t geo_bytes   = align256((size_t)E * sizeof(ushort4));
    const size_t gcnt_bytes  = align256((size_t)M * sizeof(unsigned));
    const size_t bsum_bytes  = align256(4096);
    const size_t bst_bytes   = align256((size_t)(NB + 1) * sizeof(unsigned));
    const size_t goff_bytes  = align256((size_t)(G + 1) * sizeof(unsigned));
    const size_t gst_bytes   = align256((size_t)G * SD * sizeof(float));

    size_t o = 0;
    char* w = (char*)d_ws;
    float* stateA   = (float*)(w + o);    o += state_bytes;
    float* stateB   = (float*)(w + o);    o += state_bytes;
    float* wst      = (float*)(w + o);    o += wst_bytes;
    int* pk         = (int*)(w + o);      o += pk_bytes;
    ushort4* geo8   = (ushort4*)(w + o);  o += geo_bytes;
    unsigned* gcnt  = (unsigned*)(w + o); o += gcnt_bytes;
    unsigned* gbase = gcnt;  // scan in-place? keep separate for safety:
    unsigned* gbase2= (unsigned*)(w + o); o += gcnt_bytes;
    unsigned* bsum  = (unsigned*)(w + o); o += bsum_bytes;
    unsigned* bstart= (unsigned*)(w + o); o += bst_bytes;
    unsigned* goff  = (unsigned*)(w + o); o += goff_bytes;
    float* gstate   = (float*)(w + o);    o += gst_bytes;
    gbase = gbase2;

    if (o <= ws_size && NB <= MAXNB && nb1 <= 256 && N < (1 << 18)) {
        // ---- build (no global atomics) ----
        bucket_count_kernel<<<EB, CTHR, 0, stream>>>(nto, gcnt, E, NB);
        scan1_kernel<<<nb1, 256, 0, stream>>>(gcnt, gbase, bsum, M);
        scan2_kernel<<<1, 256, 0, stream>>>(bsum, nb1);
        scan_add_kernel<<<(M + 255) / 256, 256, 0, stream>>>(gbase, bsum, M);
        bstart_kernel<<<(NB + 256) / 256, 256, 0, stream>>>(gbase, bstart, NB, E);
        bucket_scatter_kernel<<<EB, CTHR, 0, stream>>>(coords, elen, evec, nfrom, nto,
                                                       gbase, pk, geo8, E, NB);
        // ---- rounds ----
        round_bucket_kernel<true><<<NB, BLK, 0, stream>>>(bstart, pk, geo8, Wm, bm,
                                                          wst, stateB, stateA, N);
        wstate_kernel<<<ng, BLK, 0, stream>>>(stateA, Wm, bm, wst, N);
        round_bucket_kernel<false><<<NB, BLK, 0, stream>>>(bstart, pk, geo8, Wm, bm,
                                                           wst, stateA, stateB, N);
        wstate_kernel<<<ng, BLK, 0, stream>>>(stateB, Wm, bm, wst, N);
        round_bucket_kernel<false><<<NB, BLK, 0, stream>>>(bstart, pk, geo8, Wm, bm,
                                                           wst, stateB, stateA, N);
        // ---- graph phase ----
        goff_kernel<<<ng, BLK, 0, stream>>>(gidx, goff, N, G);
        gsum_kernel<<<(G * SD + BLK - 1) / BLK, BLK, 0, stream>>>(stateA, goff, gstate, G);
        out_kernel<<<gg, BLK, 0, stream>>>(gstate, Wo, bo, (float*)d_out, G);
    } else {
        // ---- fallback: atomic path ----
        const int eg = (E + BLK - 1) / BLK;
        float* gstateF = (float*)(w + 2 * state_bytes);
        hipMemsetAsync(stateA, 0, state_bytes, stream);
        hipMemsetAsync(gstateF, 0, (size_t)G * SD * sizeof(float), stream);
        edge_kernel_fb<true><<<eg, BLK, 0, stream>>>(coords, elen, evec, Wm, bm,
                                                     nfrom, nto, stateA, stateA, E);
        hipMemcpyAsync(stateB, stateA, state_bytes, hipMemcpyDeviceToDevice, stream);
        edge_kernel_fb<false><<<eg, BLK, 0, stream>>>(coords, elen, evec, Wm, bm,
                                                      nfrom, nto, stateA, stateB, E);
        hipMemcpyAsync(stateA, stateB, state_bytes, hipMemcpyDeviceToDevice, stream);
        edge_kernel_fb<false><<<eg, BLK, 0, stream>>>(coords, elen, evec, Wm, bm,
                                                      nfrom, nto, stateB, stateA, E);
        graph_reduce_fb<<<ng, BLK, 0, stream>>>(stateA, gidx, gstateF, N);
        out_kernel<<<gg, BLK, 0, stream>>>(gstateF, Wo, bo, (float*)d_out, G);
    }
}

// Round 4
// 1609.337 us; speedup vs baseline: 1.1913x; 1.1913x over previous
//
#include <hip/hip_runtime.h>
#include <math.h>

#define SD 10
#define BB 6                  // bucket bits (nodes-per-bucket = 64)
#define BSZ 64                // nodes per bucket
#define MAXNB 3328            // LDS hist capacity; N <= 3328*64 = 212992
#define EB 512                // edge-chunk blocks for passes A/C
#define CTHR 512              // threads for passes A/C
#define WSTRIDE 16            // wst row stride (floats) -> 64B aligned rows

__device__ __forceinline__ float tanh_fast(float x) {
    float e = __expf(2.0f * x);
    float r = __builtin_amdgcn_rcpf(1.0f + e);
    return 1.0f - 2.0f * r;
}

__device__ __forceinline__ float softplus_f(float x) {
    return fmaxf(x, 0.0f) + log1pf(expf(-fabsf(x)));
}

__device__ __forceinline__ unsigned short bf16_of(float x) {
    unsigned u = __float_as_uint(x);
    u = (u + 0x7FFFu + ((u >> 16) & 1u)) >> 16;   // RNE
    return (unsigned short)u;
}

// ===================== prep =====================

__global__ __launch_bounds__(256) void coords4_kernel(
    const float* __restrict__ coords, float4* __restrict__ coords4, int N)
{
    int n = blockIdx.x * blockDim.x + threadIdx.x;
    if (n >= N) return;
    float4 c;
    c.x = coords[n * 3 + 0];
    c.y = coords[n * 3 + 1];
    c.z = coords[n * 3 + 2];
    c.w = 0.0f;
    coords4[n] = c;
}

// ===================== build: deterministic multi-split =====================

// Pass A: per-block bucket histogram -> gcnt[k*EB + b]  (bucket-major)
__global__ __launch_bounds__(CTHR) void bucket_count_kernel(
    const int* __restrict__ nto, unsigned* __restrict__ gcnt, int E, int NB)
{
    __shared__ unsigned h[MAXNB];
    int b = blockIdx.x;
    for (int i = threadIdx.x; i < NB; i += CTHR) h[i] = 0;
    __syncthreads();
    long long ebeg = (long long)E * b / EB;
    long long eend = (long long)E * (b + 1) / EB;
    for (long long e = ebeg + threadIdx.x; e < eend; e += CTHR)
        atomicAdd(&h[((unsigned)nto[e]) >> BB], 1u);
    __syncthreads();
    for (int k = threadIdx.x; k < NB; k += CTHR) gcnt[(size_t)k * EB + b] = h[k];
}

// Exclusive scan, level: 1024 items per 256-thread block. (no __restrict__: called in-place)
__global__ __launch_bounds__(256) void scan1_kernel(
    const unsigned* cnt, unsigned* off, unsigned* bsum, int M)
{
    __shared__ unsigned lds[256];
    int t = threadIdx.x, b = blockIdx.x;
    int base = b * 1024 + t * 4;
    unsigned v[4], s = 0;
#pragma unroll
    for (int k = 0; k < 4; k++) {
        v[k] = (base + k < M) ? cnt[base + k] : 0u;
        s += v[k];
    }
    lds[t] = s;
    __syncthreads();
    for (int d = 1; d < 256; d <<= 1) {
        unsigned x = (t >= d) ? lds[t - d] : 0u;
        __syncthreads();
        lds[t] += x;
        __syncthreads();
    }
    unsigned excl = (t > 0) ? lds[t - 1] : 0u;
    if (t == 255) bsum[b] = lds[255];
    unsigned run = excl;
#pragma unroll
    for (int k = 0; k < 4; k++) {
        if (base + k < M) off[base + k] = run;
        run += v[k];
    }
}

__global__ __launch_bounds__(256) void scan2_kernel(unsigned* __restrict__ bsum, int nb)
{
    __shared__ unsigned lds[256];
    int t = threadIdx.x;
    unsigned v = (t < nb) ? bsum[t] : 0u;
    lds[t] = v;
    __syncthreads();
    for (int d = 1; d < 256; d <<= 1) {
        unsigned x = (t >= d) ? lds[t - d] : 0u;
        __syncthreads();
        lds[t] += x;
        __syncthreads();
    }
    unsigned excl = (t > 0) ? lds[t - 1] : 0u;
    if (t < nb) bsum[t] = excl;
}

__global__ __launch_bounds__(256) void scan_add_kernel(
    unsigned* __restrict__ off, const unsigned* __restrict__ bsum, int M)
{
    int i = blockIdx.x * blockDim.x + threadIdx.x;
    if (i < M) off[i] += bsum[i >> 10];
}

// bstart[k] = first payload index of bucket k; bstart[NB] = E
__global__ __launch_bounds__(256) void bstart_kernel(
    const unsigned* __restrict__ gbase, unsigned* __restrict__ bstart, int NB, int E)
{
    int k = blockIdx.x * blockDim.x + threadIdx.x;
    if (k > NB) return;
    bstart[k] = (k < NB) ? gbase[(size_t)k * EB] : (unsigned)E;
}

// Pass C: emit bucket-sorted 16B payload {nf|lnt<<18, bf16 g0g1, bf16 g2g3, 0}
__global__ __launch_bounds__(CTHR) void bucket_scatter_kernel(
    const float4* __restrict__ coords4,
    const float* __restrict__ elen,
    const float* __restrict__ evec,
    const int* __restrict__ nfrom,
    const int* __restrict__ nto,
    const unsigned* __restrict__ gbase,
    uint4* __restrict__ payload,
    int E, int NB)
{
    __shared__ unsigned cur[MAXNB];
    int b = blockIdx.x;
    for (int k = threadIdx.x; k < NB; k += CTHR) cur[k] = gbase[(size_t)k * EB + b];
    __syncthreads();
    long long ebeg = (long long)E * b / EB;
    long long eend = (long long)E * (b + 1) / EB;
    for (long long e = ebeg + threadIdx.x; e < eend; e += CTHR) {
        int nf = nfrom[e];
        int nt = nto[e];
        unsigned k = ((unsigned)nt) >> BB;
        unsigned pos = atomicAdd(&cur[k], 1u);

        float4 cf = coords4[nf];
        float4 ct = coords4[nt];
        float ev0 = evec[e * 3 + 0], ev1 = evec[e * 3 + 1], ev2 = evec[e * 3 + 2];

        float g0 = elen[e];
        float g1 = fabsf(cf.x) + fabsf(cf.y) + fabsf(cf.z);
        float g2 = cf.x * ct.x + cf.y * ct.y + cf.z * ct.z;
        float g3 = cf.x * ev0 + cf.y * ev1 + cf.z * ev2;

        uint4 p;
        p.x = (unsigned)nf | (((unsigned)nt & (BSZ - 1)) << 18);
        p.y = (unsigned)bf16_of(g0) | ((unsigned)bf16_of(g1) << 16);
        p.z = (unsigned)bf16_of(g2) | ((unsigned)bf16_of(g3) << 16);
        p.w = 0u;
        payload[pos] = p;
    }
}

// ===================== rounds =====================

// wst[n][j] = bm[j] + sum_k state[n][k] * Wm[k][j], row stride WSTRIDE (64B)
__global__ __launch_bounds__(256) void wstate_kernel(
    const float* __restrict__ state, const float* __restrict__ Wm,
    const float* __restrict__ bm, float* __restrict__ wst, int N)
{
    int n = blockIdx.x * blockDim.x + threadIdx.x;
    if (n >= N) return;
    const float2* sp = (const float2*)(state + (size_t)n * SD);
    float s[SD];
#pragma unroll
    for (int h = 0; h < 5; h++) { float2 v = sp[h]; s[2*h] = v.x; s[2*h+1] = v.y; }
    float t[SD];
#pragma unroll
    for (int j = 0; j < SD; j++) t[j] = bm[j];
#pragma unroll
    for (int k = 0; k < SD; k++) {
#pragma unroll
        for (int j = 0; j < SD; j++) t[j] += s[k] * Wm[k * SD + j];
    }
    float* dp = wst + (size_t)n * WSTRIDE;
#pragma unroll
    for (int j = 0; j < SD; j++) dp[j] = t[j];
}

// Wave-cooperative: 10 lanes per edge, 6 edges per wave. Lane j reads wst[nf][j]
// (coalesced 40B from one 64B line), computes 4 FMA + 1 tanh, 1 LDS atomic.
template <bool FIRST>
__global__ __launch_bounds__(256) void round_wave_kernel(
    const unsigned* __restrict__ bstart,
    const uint4* __restrict__ payload,
    const float* __restrict__ Wm,
    const float* __restrict__ bm,
    const float* __restrict__ wst,        // (N, WSTRIDE), incl bias
    const float* __restrict__ state_prev,
    float* __restrict__ state_next,
    int N)
{
    __shared__ float acc[BSZ * SD];       // 2.56 KB
    int k = blockIdx.x;
    for (int i = threadIdx.x; i < BSZ * SD; i += 256) acc[i] = 0.0f;

    int lane = threadIdx.x & 63;
    int wv = threadIdx.x >> 6;            // 0..3
    int grp = lane / 10;                  // 0..5 (6 edges), lanes 60..63 idle
    int j = lane - grp * 10;              // 0..9
    bool active = (lane < 60);

    float w0 = Wm[10 * SD + j];
    float w1 = Wm[11 * SD + j];
    float w2 = Wm[12 * SD + j];
    float w3 = Wm[13 * SD + j];
    float bb = bm[j];
    __syncthreads();

    unsigned beg = bstart[k], end = bstart[k + 1];
    for (unsigned i0 = beg + wv * 6; i0 < end; i0 += 24) {
        unsigned e = i0 + (unsigned)grp;
        if (active && e < end) {
            uint4 p = payload[e];
            int nf  = (int)(p.x & 0x3FFFFu);
            int lnt = (int)((p.x >> 18) & (BSZ - 1));
            float g0 = __uint_as_float(p.y << 16);
            float g1 = __uint_as_float(p.y & 0xFFFF0000u);
            float g2 = __uint_as_float(p.z << 16);
            float g3 = __uint_as_float(p.z & 0xFFFF0000u);
            float t = FIRST ? bb : wst[(size_t)nf * WSTRIDE + j];
            t += g0 * w0 + g1 * w1 + g2 * w2 + g3 * w3;
            atomicAdd(&acc[lnt * SD + j], tanh_fast(t));
        }
    }
    __syncthreads();

    int base = k * BSZ * SD;
    int lim = N * SD - base;
    for (int i = threadIdx.x; i < BSZ * SD; i += 256) {
        if (i < lim) {
            float v = acc[i];
            if (!FIRST) v += state_prev[base + i];
            state_next[base + i] = v;
        }
    }
}

// ===================== graph phase =====================

__global__ __launch_bounds__(256) void goff_kernel(
    const int* __restrict__ gidx, unsigned* __restrict__ goff, int N, int G)
{
    int n = blockIdx.x * blockDim.x + threadIdx.x;
    if (n >= N) return;
    int g = gidx[n];
    if (n == 0) {
        for (int q = 0; q <= g; q++) goff[q] = 0;
    } else {
        int gp = gidx[n - 1];
        for (int q = gp + 1; q <= g; q++) goff[q] = (unsigned)n;
    }
    if (n == N - 1) {
        for (int q = g + 1; q <= G; q++) goff[q] = (unsigned)N;
    }
}

// 4-way split per (g,j); one atomic per partial. gstate must be zeroed.
__global__ __launch_bounds__(256) void gsum_kernel(
    const float* __restrict__ state, const unsigned* __restrict__ goff,
    float* __restrict__ gstate, int G)
{
    int tid = blockIdx.x * blockDim.x + threadIdx.x;
    if (tid >= G * SD * 4) return;
    int s = tid & 3;
    int rest = tid >> 2;
    int g = rest / SD;
    int j = rest - g * SD;
    unsigned beg = goff[g], end = goff[g + 1];
    unsigned len = end - beg;
    unsigned b0 = beg + (len * (unsigned)s) / 4u;
    unsigned b1 = beg + (len * (unsigned)(s + 1)) / 4u;
    float a = 0.0f;
    for (unsigned n = b0; n < b1; n++) a += state[(size_t)n * SD + j];
    atomicAdd(&gstate[(size_t)g * SD + j], a);
}

__global__ __launch_bounds__(256) void out_kernel(
    const float* __restrict__ gstate, const float* __restrict__ Wo,
    const float* __restrict__ bo, float* __restrict__ out, int G)
{
    int g = blockIdx.x * blockDim.x + threadIdx.x;
    if (g >= G) return;
    float s[SD];
#pragma unroll
    for (int k = 0; k < SD; k++) s[k] = gstate[(size_t)g * SD + k];
    float ev[4];
#pragma unroll
    for (int c = 0; c < 4; c++) {
        float a = bo[c];
#pragma unroll
        for (int k = 0; k < SD; k++) a += s[k] * Wo[k * 4 + c];
        ev[c] = a;
    }
    out[g * 4 + 0] = ev[0];
    out[g * 4 + 1] = softplus_f(ev[1]);
    out[g * 4 + 2] = softplus_f(ev[2]) + 1.0f;
    out[g * 4 + 3] = softplus_f(ev[3]);
}

// ===================== fallback (atomic path) =====================

template <bool FIRST>
__global__ __launch_bounds__(256) void edge_kernel_fb(
    const float* __restrict__ coords, const float* __restrict__ elen,
    const float* __restrict__ evec, const float* __restrict__ Wm,
    const float* __restrict__ bm, const int* __restrict__ nfrom,
    const int* __restrict__ nto, const float* __restrict__ state_prev,
    float* __restrict__ state_next, int E)
{
    int e = blockIdx.x * blockDim.x + threadIdx.x;
    if (e >= E) return;
    int nf = nfrom[e];
    int nt = nto[e];
    float cf0 = coords[nf*3+0], cf1 = coords[nf*3+1], cf2 = coords[nf*3+2];
    float ct0 = coords[nt*3+0], ct1 = coords[nt*3+1], ct2 = coords[nt*3+2];
    float ev0 = evec[e*3+0], ev1 = evec[e*3+1], ev2 = evec[e*3+2];
    float g0 = elen[e];
    float g1 = fabsf(cf0) + fabsf(cf1) + fabsf(cf2);
    float g2 = cf0*ct0 + cf1*ct1 + cf2*ct2;
    float g3 = cf0*ev0 + cf1*ev1 + cf2*ev2;
    float acc[SD];
#pragma unroll
    for (int j = 0; j < SD; j++) {
        acc[j] = bm[j] + g0*Wm[10*SD+j] + g1*Wm[11*SD+j] + g2*Wm[12*SD+j] + g3*Wm[13*SD+j];
    }
    if (!FIRST) {
        const float2* sp = (const float2*)(state_prev + (size_t)nf * SD);
        float s[SD];
#pragma unroll
        for (int h = 0; h < 5; h++) { float2 v = sp[h]; s[2*h] = v.x; s[2*h+1] = v.y; }
#pragma unroll
        for (int k = 0; k < SD; k++) {
#pragma unroll
            for (int j = 0; j < SD; j++) acc[j] += s[k] * Wm[k*SD+j];
        }
    }
    float* dst = state_next + (size_t)nt * SD;
#pragma unroll
    for (int j = 0; j < SD; j++) atomicAdd(dst + j, tanh_fast(acc[j]));
}

__global__ __launch_bounds__(256) void graph_reduce_fb(
    const float* __restrict__ state, const int* __restrict__ gidx,
    float* __restrict__ gstate, int N)
{
    int n = blockIdx.x * blockDim.x + threadIdx.x;
    if (n >= N) return;
    int g = gidx[n];
    const float2* sp = (const float2*)(state + (size_t)n * SD);
    float* dst = gstate + (size_t)g * SD;
#pragma unroll
    for (int h = 0; h < 5; h++) {
        float2 v = sp[h];
        atomicAdd(dst + 2*h, v.x);
        atomicAdd(dst + 2*h + 1, v.y);
    }
}

// ===================== launch =====================

extern "C" void kernel_launch(void* const* d_in, const int* in_sizes, int n_in,
                              void* d_out, int out_size, void* d_ws, size_t ws_size,
                              hipStream_t stream) {
    const float* coords = (const float*)d_in[0];
    const float* elen   = (const float*)d_in[1];
    const float* evec   = (const float*)d_in[2];
    const float* Wm     = (const float*)d_in[3];
    const float* bm     = (const float*)d_in[4];
    const float* Wo     = (const float*)d_in[5];
    const float* bo     = (const float*)d_in[6];
    const int* nfrom    = (const int*)d_in[7];
    const int* nto      = (const int*)d_in[8];
    const int* gidx     = (const int*)d_in[9];

    const int E = in_sizes[1];
    const int N = in_sizes[9];
    const int G = out_size / 4;

    const int NB  = (N + BSZ - 1) / BSZ;     // buckets
    const int M   = NB * EB;                 // scan length
    const int nb1 = (M + 1023) / 1024;       // scan level-1 blocks
    const int nb2 = (nb1 + 1023) / 1024;     // scan level-2 blocks

    const int BLK = 256;
    const int ng = (N + BLK - 1) / BLK;
    const int gg = (G + BLK - 1) / BLK;

    auto align256 = [](size_t x) { return (x + 255) & ~(size_t)255; };
    const size_t state_bytes = align256((size_t)N * SD * sizeof(float));
    const size_t wst_bytes   = align256((size_t)N * WSTRIDE * sizeof(float));
    const size_t pay_bytes   = align256((size_t)E * sizeof(uint4));
    const size_t gcnt_bytes  = align256((size_t)M * sizeof(unsigned));
    const size_t bsumA_bytes = align256((size_t)nb1 * sizeof(unsigned));
    const size_t bsumB_bytes = align256((size_t)(nb2 > 0 ? nb2 : 1) * sizeof(unsigned) + 256);
    const size_t bst_bytes   = align256((size_t)(NB + 1) * sizeof(unsigned));
    const size_t goff_bytes  = align256((size_t)(G + 1) * sizeof(unsigned));
    const size_t gst_bytes   = align256((size_t)G * SD * sizeof(float));
    const size_t c4_bytes    = align256((size_t)N * sizeof(float4));

    size_t o = 0;
    char* w = (char*)d_ws;
    float* stateA    = (float*)(w + o);    o += state_bytes;
    float* stateB    = (float*)(w + o);    o += state_bytes;
    float* wst       = (float*)(w + o);    o += wst_bytes;
    uint4* payload   = (uint4*)(w + o);    o += pay_bytes;
    unsigned* gcnt   = (unsigned*)(w + o); o += gcnt_bytes;
    unsigned* gbase  = (unsigned*)(w + o); o += gcnt_bytes;
    unsigned* bsumA  = (unsigned*)(w + o); o += bsumA_bytes;
    unsigned* bsumB  = (unsigned*)(w + o); o += bsumB_bytes;
    unsigned* bstart = (unsigned*)(w + o); o += bst_bytes;
    unsigned* goff   = (unsigned*)(w + o); o += goff_bytes;
    float* gstate    = (float*)(w + o);    o += gst_bytes;
    float4* coords4  = (float4*)(w + o);   o += c4_bytes;

    if (o <= ws_size && NB <= MAXNB && nb1 <= 1024 * 256 && nb2 <= 256 && N < (1 << 18)) {
        // ---- prep + build (no global atomics) ----
        coords4_kernel<<<ng, BLK, 0, stream>>>(coords, coords4, N);
        bucket_count_kernel<<<EB, CTHR, 0, stream>>>(nto, gcnt, E, NB);
        scan1_kernel<<<nb1, 256, 0, stream>>>(gcnt, gbase, bsumA, M);
        scan1_kernel<<<nb2, 256, 0, stream>>>(bsumA, bsumA, bsumB, nb1);   // in-place OK
        scan2_kernel<<<1, 256, 0, stream>>>(bsumB, nb2);
        scan_add_kernel<<<(nb1 + 255) / 256, 256, 0, stream>>>(bsumA, bsumB, nb1);
        scan_add_kernel<<<(M + 255) / 256, 256, 0, stream>>>(gbase, bsumA, M);
        bstart_kernel<<<(NB + 256) / 256, 256, 0, stream>>>(gbase, bstart, NB, E);
        bucket_scatter_kernel<<<EB, CTHR, 0, stream>>>(coords4, elen, evec, nfrom, nto,
                                                       gbase, payload, E, NB);
        // ---- rounds ----
        round_wave_kernel<true><<<NB, BLK, 0, stream>>>(bstart, payload, Wm, bm,
                                                        wst, stateB, stateA, N);
        wstate_kernel<<<ng, BLK, 0, stream>>>(stateA, Wm, bm, wst, N);
        round_wave_kernel<false><<<NB, BLK, 0, stream>>>(bstart, payload, Wm, bm,
                                                         wst, stateA, stateB, N);
        wstate_kernel<<<ng, BLK, 0, stream>>>(stateB, Wm, bm, wst, N);
        round_wave_kernel<false><<<NB, BLK, 0, stream>>>(bstart, payload, Wm, bm,
                                                         wst, stateB, stateA, N);
        // ---- graph phase ----
        hipMemsetAsync(gstate, 0, (size_t)G * SD * sizeof(float), stream);
        goff_kernel<<<ng, BLK, 0, stream>>>(gidx, goff, N, G);
        gsum_kernel<<<(G * SD * 4 + BLK - 1) / BLK, BLK, 0, stream>>>(stateA, goff, gstate, G);
        out_kernel<<<gg, BLK, 0, stream>>>(gstate, Wo, bo, (float*)d_out, G);
    } else {
        // ---- fallback: atomic path ----
        const int eg = (E + BLK - 1) / BLK;
        float* gstateF = (float*)(w + 2 * state_bytes);
        hipMemsetAsync(stateA, 0, state_bytes, stream);
        hipMemsetAsync(gstateF, 0, (size_t)G * SD * sizeof(float), stream);
        edge_kernel_fb<true><<<eg, BLK, 0, stream>>>(coords, elen, evec, Wm, bm,
                                                     nfrom, nto, stateA, stateA, E);
        hipMemcpyAsync(stateB, stateA, state_bytes, hipMemcpyDeviceToDevice, stream);
        edge_kernel_fb<false><<<eg, BLK, 0, stream>>>(coords, elen, evec, Wm, bm,
                                                      nfrom, nto, stateA, stateB, E);
        hipMemcpyAsync(stateA, stateB, state_bytes, hipMemcpyDeviceToDevice, stream);
        edge_kernel_fb<false><<<eg, BLK, 0, stream>>>(coords, elen, evec, Wm, bm,
                                                      nfrom, nto, stateB, stateA, E);
        graph_reduce_fb<<<ng, BLK, 0, stream>>>(stateA, gidx, gstateF, N);
        out_kernel<<<gg, BLK, 0, stream>>>(gstateF, Wo, bo, (float*)d_out, G);
    }
}